// Round 1
// baseline (1452.532 us; speedup 1.0000x reference)
//
#include <hip/hip_runtime.h>

// MultiHeadAttention: per-token MHA over head axis.
// Round 1: bf16-MFMA baseline. cast -> QKV gemm (128x128 tile, global_load_lds)
// -> per-token attention (1 wave/token) -> output gemm (fp32 + bias).

using u16 = unsigned short;
using u32 = unsigned int;

typedef __attribute__((ext_vector_type(8))) short bf16x8;
typedef __attribute__((ext_vector_type(4))) float f32x4;
typedef __attribute__((ext_vector_type(4))) u32 u32x4;
typedef __attribute__((ext_vector_type(8))) u16 u16x8;

// fp32 -> bf16 round-to-nearest-even (inputs are finite normals; no NaN path)
__device__ __forceinline__ u16 f2bf(float f) {
  u32 u = __builtin_bit_cast(u32, f);
  u32 r = u + 0x7fffu + ((u >> 16) & 1u);
  return (u16)(r >> 16);
}
__device__ __forceinline__ float bflo(u32 u) { return __builtin_bit_cast(float, u << 16); }
__device__ __forceinline__ float bfhi(u32 u) { return __builtin_bit_cast(float, u & 0xffff0000u); }

// async global->LDS, 16B per lane. LDS dest is wave-uniform base + lane*16;
// global src is per-lane (guide §5, m97/m104).
__device__ __forceinline__ void gld_lds16(const void* g, void* l) {
  __builtin_amdgcn_global_load_lds((const __attribute__((address_space(1))) void*)g,
                                   (__attribute__((address_space(3))) void*)l, 16, 0, 0);
}

// ---------------- cast kernels ----------------
__global__ void cast_kernel(const float* __restrict__ in, u16* __restrict__ out, long n) {
  long i = ((long)blockIdx.x * blockDim.x + threadIdx.x) * 8;
  if (i >= n) return;
  float4 a = *(const float4*)(in + i);
  float4 b = *(const float4*)(in + i + 4);
  u16x8 o;
  o[0] = f2bf(a.x); o[1] = f2bf(a.y); o[2] = f2bf(a.z); o[3] = f2bf(a.w);
  o[4] = f2bf(b.x); o[5] = f2bf(b.y); o[6] = f2bf(b.z); o[7] = f2bf(b.w);
  *(u16x8*)(out + i) = o;
}

__global__ void cast_w4(const float* __restrict__ w0, const float* __restrict__ w1,
                        const float* __restrict__ w2, const float* __restrict__ w3,
                        u16* __restrict__ o0, u16* __restrict__ o1,
                        u16* __restrict__ o2, u16* __restrict__ o3) {
  const float* in; u16* out;
  switch (blockIdx.y) {
    case 0: in = w0; out = o0; break;
    case 1: in = w1; out = o1; break;
    case 2: in = w2; out = o2; break;
    default: in = w3; out = o3; break;
  }
  long i = ((long)blockIdx.x * blockDim.x + threadIdx.x) * 8;  // 1M els, 512 blocks
  float4 a = *(const float4*)(in + i);
  float4 b = *(const float4*)(in + i + 4);
  u16x8 o;
  o[0] = f2bf(a.x); o[1] = f2bf(a.y); o[2] = f2bf(a.z); o[3] = f2bf(a.w);
  o[4] = f2bf(b.x); o[5] = f2bf(b.y); o[6] = f2bf(b.z); o[7] = f2bf(b.w);
  *(u16x8*)(out + i) = o;
}

// ---------------- GEMM: C[m][n] = sum_k A[m][k] * B[n][k] + bias[n] ----------------
// 128x128 tile, BK=64, 256 threads (4 waves, 2x2 wave grid, 64x64 per wave),
// mfma_f32_16x16x32_bf16, acc 4x4 frags. Single LDS buffer, 2 barriers/K-step (m97 structure).
template <bool F32OUT>
__global__ __launch_bounds__(256)
void gemm_bt(const u16* __restrict__ A,
             const u16* __restrict__ B0, const u16* __restrict__ B1, const u16* __restrict__ B2,
             const float* __restrict__ bias0, const float* __restrict__ bias1,
             const float* __restrict__ bias2,
             void* out0, void* out1, void* out2, int N, int K) {
  __shared__ __align__(16) u16 sA[128 * 64];
  __shared__ __align__(16) u16 sB[128 * 64];

  const int tid = threadIdx.x;
  const int w = tid >> 6;
  const int lane = tid & 63;
  const int z = blockIdx.z;
  const u16* B = (z == 0) ? B0 : (z == 1) ? B1 : B2;
  const float* bias = (z == 0) ? bias0 : (z == 1) ? bias1 : bias2;
  void* out = (z == 0) ? out0 : (z == 1) ? out1 : out2;

  const int col0 = blockIdx.x * 128;  // x fastest: consecutive blocks share A-panel in L2
  const int row0 = blockIdx.y * 128;

  // staging: 16 chunks of 1KB each per operand; wave w does chunks w+4i.
  // chunk c = rows [c*8, c*8+8) x 64 k. lane covers row c*8+(lane>>3), k (lane&7)*8.
  const int srow = lane >> 3;
  const int scol = (lane & 7) * 8;
  const u16* gA = A + (size_t)(row0 + srow) * K + scol;
  const u16* gB = B + (size_t)(col0 + srow) * K + scol;

  // fragment addressing: row (lane&15), k-chunk (lane>>4)*8
  const int lr = lane >> 4, lc = lane & 15;
  const int wm = w >> 1, wn = w & 1;
  const u16* aP = &sA[(wm * 64 + lc) * 64 + lr * 8];
  const u16* bP = &sB[(wn * 64 + lc) * 64 + lr * 8];

  f32x4 acc[4][4];
#pragma unroll
  for (int i = 0; i < 4; ++i)
#pragma unroll
    for (int j = 0; j < 4; ++j) acc[i][j] = (f32x4){0.f, 0.f, 0.f, 0.f};

  for (int kt = 0; kt < K; kt += 64) {
#pragma unroll
    for (int i = 0; i < 4; ++i) {
      const int c = w + i * 4;
      gld_lds16(gA + (size_t)c * 8 * K + kt, &sA[c * 512]);
      gld_lds16(gB + (size_t)c * 8 * K + kt, &sB[c * 512]);
    }
    __syncthreads();  // drains vmcnt before barrier (compiler-inserted)
#pragma unroll
    for (int kk = 0; kk < 2; ++kk) {
      bf16x8 av[4], bv[4];
#pragma unroll
      for (int mi = 0; mi < 4; ++mi) av[mi] = *(const bf16x8*)(aP + mi * 16 * 64 + kk * 32);
#pragma unroll
      for (int ni = 0; ni < 4; ++ni) bv[ni] = *(const bf16x8*)(bP + ni * 16 * 64 + kk * 32);
#pragma unroll
      for (int mi = 0; mi < 4; ++mi)
#pragma unroll
        for (int ni = 0; ni < 4; ++ni)
          acc[mi][ni] =
              __builtin_amdgcn_mfma_f32_16x16x32_bf16(av[mi], bv[ni], acc[mi][ni], 0, 0, 0);
    }
    __syncthreads();
  }

  // epilogue: D col = lane&15, row = (lane>>4)*4 + j (verified layout, guide §3)
#pragma unroll
  for (int ni = 0; ni < 4; ++ni) {
    const int col = col0 + wn * 64 + ni * 16 + lc;
    const float bv = bias[col];
#pragma unroll
    for (int mi = 0; mi < 4; ++mi) {
      const int row = row0 + wm * 64 + mi * 16 + lr * 4;
      const f32x4 v = acc[mi][ni];
#pragma unroll
      for (int j = 0; j < 4; ++j) {
        const float val = v[j] + bv;
        if (F32OUT)
          ((float*)out)[(size_t)(row + j) * N + col] = val;
        else
          ((u16*)out)[(size_t)(row + j) * N + col] = f2bf(val);
      }
    }
  }
}

// ---------------- per-token attention ----------------
// 1 wave per token. lane = q*4 + p: query head q (0..15), dim-quarter p (0..3).
__device__ __forceinline__ void unpack8(const u32x4 v, float* f) {
#pragma unroll
  for (int i = 0; i < 4; ++i) { f[2 * i] = bflo(v[i]); f[2 * i + 1] = bfhi(v[i]); }
}

__global__ __launch_bounds__(256)
void attn_kernel(const u16* __restrict__ Q, const u16* __restrict__ K,
                 const u16* __restrict__ V, u16* __restrict__ O) {
  __shared__ __align__(16) u16 sm[4][3][1024];  // [wave][q/k/v][16*64] = 24KB
  const int tid = threadIdx.x;
  const int w = tid >> 6, lane = tid & 63;
  const long t = (long)blockIdx.x * 4 + w;

  {  // cooperative stage: 2KB per array per wave, fully coalesced 16B/lane
    const u32x4* gq = (const u32x4*)(Q + t * 1024);
    const u32x4* gk = (const u32x4*)(K + t * 1024);
    const u32x4* gv = (const u32x4*)(V + t * 1024);
    u32x4* lq = (u32x4*)sm[w][0];
    u32x4* lk = (u32x4*)sm[w][1];
    u32x4* lv = (u32x4*)sm[w][2];
    lq[lane] = gq[lane]; lq[lane + 64] = gq[lane + 64];
    lk[lane] = gk[lane]; lk[lane + 64] = gk[lane + 64];
    lv[lane] = gv[lane]; lv[lane + 64] = gv[lane + 64];
  }
  __syncthreads();

  const int q = lane >> 2;
  const int p = lane & 3;

  float qv[16];
  {
    const u32x4* Qr = (const u32x4*)&sm[w][0][q * 64 + p * 16];
    unpack8(Qr[0], qv); unpack8(Qr[1], qv + 8);
  }

  float s[16];
#pragma unroll
  for (int k = 0; k < 16; ++k) {
    const u32x4* Kr = (const u32x4*)&sm[w][1][k * 64 + p * 16];
    float kv[16];
    unpack8(Kr[0], kv); unpack8(Kr[1], kv + 8);
    float d = 0.f;
#pragma unroll
    for (int i = 0; i < 16; ++i) d = fmaf(qv[i], kv[i], d);
    d += __shfl_xor(d, 1);  // reduce over dim-quarters
    d += __shfl_xor(d, 2);
    s[k] = d * 0.125f;  // 1/sqrt(64)
  }

  float m = s[0];
#pragma unroll
  for (int k = 1; k < 16; ++k) m = fmaxf(m, s[k]);
  float sum = 0.f;
#pragma unroll
  for (int k = 0; k < 16; ++k) { s[k] = exp2f((s[k] - m) * 1.44269504f); sum += s[k]; }
  const float inv = 1.0f / sum;

  float acc[16];
#pragma unroll
  for (int i = 0; i < 16; ++i) acc[i] = 0.f;
#pragma unroll
  for (int k = 0; k < 16; ++k) {
    const u32x4* Vr = (const u32x4*)&sm[w][2][k * 64 + p * 16];
    float vv[16];
    unpack8(Vr[0], vv); unpack8(Vr[1], vv + 8);
    const float pw = s[k] * inv;
#pragma unroll
    for (int i = 0; i < 16; ++i) acc[i] = fmaf(pw, vv[i], acc[i]);
  }

  u16* Or = O + t * 1024 + q * 64 + p * 16;
#pragma unroll
  for (int h = 0; h < 2; ++h) {
    u16x8 o;
#pragma unroll
    for (int i = 0; i < 8; ++i) o[i] = f2bf(acc[h * 8 + i]);
    *(u16x8*)(Or + h * 8) = o;
  }
}

// ---------------- launch ----------------
extern "C" void kernel_launch(void* const* d_in, const int* in_sizes, int n_in,
                              void* d_out, int out_size, void* d_ws, size_t ws_size,
                              hipStream_t stream) {
  const float* H  = (const float*)d_in[0];
  const float* Wq = (const float*)d_in[1];
  const float* bq = (const float*)d_in[2];
  const float* Wk = (const float*)d_in[3];
  const float* bk = (const float*)d_in[4];
  const float* Wv = (const float*)d_in[5];
  const float* bv = (const float*)d_in[6];
  const float* Wo = (const float*)d_in[7];
  const float* bo = (const float*)d_in[8];

  const int M = in_sizes[0] / 1024;  // 65536 tokens
  const int K = 1024, N = 1024;
  const size_t sz = (size_t)M * 1024;

  u16* ws  = (u16*)d_ws;
  u16* Hb  = ws;            // M*1024 bf16 (reused as attended after QKV gemms)
  u16* Qb  = ws + sz;
  u16* Kb  = ws + 2 * sz;
  u16* Vb  = ws + 3 * sz;
  u16* Wqb = ws + 4 * sz;
  u16* Wkb = Wqb + (1 << 20);
  u16* Wvb = Wqb + 2 * (1 << 20);
  u16* Wob = Wqb + 3 * (1 << 20);
  u16* Ab  = Hb;

  const long nH = (long)M * 1024;
  cast_kernel<<<dim3(nH / 2048), dim3(256), 0, stream>>>(H, Hb, nH);
  cast_w4<<<dim3(512, 4), dim3(256), 0, stream>>>(Wq, Wk, Wv, Wo, Wqb, Wkb, Wvb, Wob);

  gemm_bt<false><<<dim3(N / 128, M / 128, 3), dim3(256), 0, stream>>>(
      Hb, Wqb, Wkb, Wvb, bq, bk, bv, Qb, Kb, Vb, N, K);

  attn_kernel<<<dim3(M / 4), dim3(256), 0, stream>>>(Qb, Kb, Vb, Ab);

  gemm_bt<true><<<dim3(N / 128, M / 128, 1), dim3(256), 0, stream>>>(
      Ab, Wob, Wob, Wob, bo, bo, bo, d_out, d_out, d_out, N, K);
}

// Round 2
// 1411.249 us; speedup vs baseline: 1.0293x; 1.0293x over previous
//
#include <hip/hip_runtime.h>

// MultiHeadAttention: per-token MHA over head axis.
// Round 2: fix 16-way LDS bank conflicts in GEMM via XOR-swizzle
// (pre-swizzled global source + swizzled ds_read, rule #21), and add
// bijective XCD-aware block swizzle (T1) for A-panel L2 locality.

using u16 = unsigned short;
using u32 = unsigned int;

typedef __attribute__((ext_vector_type(8))) short bf16x8;
typedef __attribute__((ext_vector_type(4))) float f32x4;
typedef __attribute__((ext_vector_type(4))) u32 u32x4;
typedef __attribute__((ext_vector_type(8))) u16 u16x8;

// fp32 -> bf16 round-to-nearest-even (inputs are finite normals; no NaN path)
__device__ __forceinline__ u16 f2bf(float f) {
  u32 u = __builtin_bit_cast(u32, f);
  u32 r = u + 0x7fffu + ((u >> 16) & 1u);
  return (u16)(r >> 16);
}
__device__ __forceinline__ float bflo(u32 u) { return __builtin_bit_cast(float, u << 16); }
__device__ __forceinline__ float bfhi(u32 u) { return __builtin_bit_cast(float, u & 0xffff0000u); }

// async global->LDS, 16B per lane. LDS dest is wave-uniform base + lane*16;
// global src is per-lane (guide §5, m97/m104/m173).
__device__ __forceinline__ void gld_lds16(const void* g, void* l) {
  __builtin_amdgcn_global_load_lds((const __attribute__((address_space(1))) void*)g,
                                   (__attribute__((address_space(3))) void*)l, 16, 0, 0);
}

// ---------------- cast kernels ----------------
__global__ void cast_kernel(const float* __restrict__ in, u16* __restrict__ out, long n) {
  long i = ((long)blockIdx.x * blockDim.x + threadIdx.x) * 8;
  if (i >= n) return;
  float4 a = *(const float4*)(in + i);
  float4 b = *(const float4*)(in + i + 4);
  u16x8 o;
  o[0] = f2bf(a.x); o[1] = f2bf(a.y); o[2] = f2bf(a.z); o[3] = f2bf(a.w);
  o[4] = f2bf(b.x); o[5] = f2bf(b.y); o[6] = f2bf(b.z); o[7] = f2bf(b.w);
  *(u16x8*)(out + i) = o;
}

__global__ void cast_w4(const float* __restrict__ w0, const float* __restrict__ w1,
                        const float* __restrict__ w2, const float* __restrict__ w3,
                        u16* __restrict__ o0, u16* __restrict__ o1,
                        u16* __restrict__ o2, u16* __restrict__ o3) {
  const float* in; u16* out;
  switch (blockIdx.y) {
    case 0: in = w0; out = o0; break;
    case 1: in = w1; out = o1; break;
    case 2: in = w2; out = o2; break;
    default: in = w3; out = o3; break;
  }
  long i = ((long)blockIdx.x * blockDim.x + threadIdx.x) * 8;  // 1M els, 512 blocks
  float4 a = *(const float4*)(in + i);
  float4 b = *(const float4*)(in + i + 4);
  u16x8 o;
  o[0] = f2bf(a.x); o[1] = f2bf(a.y); o[2] = f2bf(a.z); o[3] = f2bf(a.w);
  o[4] = f2bf(b.x); o[5] = f2bf(b.y); o[6] = f2bf(b.z); o[7] = f2bf(b.w);
  *(u16x8*)(out + i) = o;
}

// ---------------- GEMM: C[m][n] = sum_k A[m][k] * B[n][k] + bias[n] ----------------
// 128x128 tile, BK=64, 256 threads (4 waves, 2x2 wave grid, 64x64 per wave),
// mfma_f32_16x16x32_bf16, acc 4x4 frags. m97 2-barrier structure.
//
// LDS swizzle (T2, rule #21 both-sides): the tile is stored in 16B granules.
// Granule (row, kg) [kg = 0..7 across the 64-elem K-slab] lives at linear
// granule  row*8 + (kg ^ (row&7)).  gld_lds writes linearly (base+lane*16),
// so the STAGING lane loads the global granule kg = (lane&7) ^ (lane>>3);
// the READ applies the same XOR: j = (lr + 4*kk) ^ (lc&7).  Per ds_read_b128
// the wave's 64 lanes then spread 8-per-16B-column = conflict-free minimum.
template <bool F32OUT>
__global__ __launch_bounds__(256)
void gemm_bt(const u16* __restrict__ A,
             const u16* __restrict__ B0, const u16* __restrict__ B1, const u16* __restrict__ B2,
             const float* __restrict__ bias0, const float* __restrict__ bias1,
             const float* __restrict__ bias2,
             void* out0, void* out1, void* out2, int N, int K) {
  __shared__ __align__(16) u16 sA[128 * 64];
  __shared__ __align__(16) u16 sB[128 * 64];

  const int tid = threadIdx.x;
  const int w = tid >> 6;
  const int lane = tid & 63;
  const int z = blockIdx.z;
  const u16* B = (z == 0) ? B0 : (z == 1) ? B1 : B2;
  const float* bias = (z == 0) ? bias0 : (z == 1) ? bias1 : bias2;
  void* out = (z == 0) ? out0 : (z == 1) ? out1 : out2;

  // T1: bijective XCD swizzle over the flattened (x,y) grid (nwg divisible by 8).
  const int nwg = gridDim.x;
  const int bid = blockIdx.x;
  const int t = (bid & 7) * (nwg >> 3) + (bid >> 3);
  const int xt = N >> 7;                 // tiles along N
  const int col0 = (t % xt) * 128;
  const int row0 = (t / xt) * 128;

  // staging: 16 chunks of 1KB per operand; wave w does chunks w+4i.
  // chunk c rows [c*8, c*8+8); lane -> row c*8+(lane>>3), granule j=lane&7,
  // which holds global kg = j ^ (row&7) = (lane&7) ^ (lane>>3).
  const int srow = lane >> 3;
  const int scol = ((lane & 7) ^ (lane >> 3)) * 8;   // pre-swizzled global source
  const u16* gA = A + (size_t)(row0 + srow) * K + scol;
  const u16* gB = B + (size_t)(col0 + srow) * K + scol;

  // fragment addressing: row lc = lane&15, k-granule lr = lane>>4
  const int lr = lane >> 4, lc = lane & 15;
  const int wm = w >> 1, wn = w & 1;
  const int aRow = (wm * 64 + lc) * 64;
  const int bRow = (wn * 64 + lc) * 64;

  f32x4 acc[4][4];
#pragma unroll
  for (int i = 0; i < 4; ++i)
#pragma unroll
    for (int j = 0; j < 4; ++j) acc[i][j] = (f32x4){0.f, 0.f, 0.f, 0.f};

  for (int kt = 0; kt < K; kt += 64) {
#pragma unroll
    for (int i = 0; i < 4; ++i) {
      const int c = w + i * 4;
      gld_lds16(gA + (size_t)c * 8 * K + kt, &sA[c * 512]);
      gld_lds16(gB + (size_t)c * 8 * K + kt, &sB[c * 512]);
    }
    __syncthreads();
#pragma unroll
    for (int kk = 0; kk < 2; ++kk) {
      const int j = ((lr + 4 * kk) ^ (lc & 7)) * 8;  // swizzled k-granule offset
      bf16x8 av[4], bv[4];
#pragma unroll
      for (int mi = 0; mi < 4; ++mi) av[mi] = *(const bf16x8*)(&sA[aRow + mi * 1024 + j]);
#pragma unroll
      for (int ni = 0; ni < 4; ++ni) bv[ni] = *(const bf16x8*)(&sB[bRow + ni * 1024 + j]);
#pragma unroll
      for (int mi = 0; mi < 4; ++mi)
#pragma unroll
        for (int ni = 0; ni < 4; ++ni)
          acc[mi][ni] =
              __builtin_amdgcn_mfma_f32_16x16x32_bf16(av[mi], bv[ni], acc[mi][ni], 0, 0, 0);
    }
    __syncthreads();
  }

  // epilogue: D col = lane&15, row = (lane>>4)*4 + j (verified layout, guide §3)
#pragma unroll
  for (int ni = 0; ni < 4; ++ni) {
    const int col = col0 + wn * 64 + ni * 16 + lc;
    const float bv = bias[col];
#pragma unroll
    for (int mi = 0; mi < 4; ++mi) {
      const int row = row0 + wm * 64 + mi * 16 + lr * 4;
      const f32x4 v = acc[mi][ni];
#pragma unroll
      for (int j = 0; j < 4; ++j) {
        const float val = v[j] + bv;
        if (F32OUT)
          ((float*)out)[(size_t)(row + j) * N + col] = val;
        else
          ((u16*)out)[(size_t)(row + j) * N + col] = f2bf(val);
      }
    }
  }
}

// ---------------- per-token attention ----------------
// 1 wave per token. lane = q*4 + p: query head q (0..15), dim-quarter p (0..3).
__device__ __forceinline__ void unpack8(const u32x4 v, float* f) {
#pragma unroll
  for (int i = 0; i < 4; ++i) { f[2 * i] = bflo(v[i]); f[2 * i + 1] = bfhi(v[i]); }
}

__global__ __launch_bounds__(256)
void attn_kernel(const u16* __restrict__ Q, const u16* __restrict__ K,
                 const u16* __restrict__ V, u16* __restrict__ O) {
  __shared__ __align__(16) u16 sm[4][3][1024];  // [wave][q/k/v][16*64] = 24KB
  const int tid = threadIdx.x;
  const int w = tid >> 6, lane = tid & 63;
  const long t = (long)blockIdx.x * 4 + w;

  {  // cooperative stage: 2KB per array per wave, fully coalesced 16B/lane
    const u32x4* gq = (const u32x4*)(Q + t * 1024);
    const u32x4* gk = (const u32x4*)(K + t * 1024);
    const u32x4* gv = (const u32x4*)(V + t * 1024);
    u32x4* lq = (u32x4*)sm[w][0];
    u32x4* lk = (u32x4*)sm[w][1];
    u32x4* lv = (u32x4*)sm[w][2];
    lq[lane] = gq[lane]; lq[lane + 64] = gq[lane + 64];
    lk[lane] = gk[lane]; lk[lane + 64] = gk[lane + 64];
    lv[lane] = gv[lane]; lv[lane + 64] = gv[lane + 64];
  }
  __syncthreads();

  const int q = lane >> 2;
  const int p = lane & 3;

  float qv[16];
  {
    const u32x4* Qr = (const u32x4*)&sm[w][0][q * 64 + p * 16];
    unpack8(Qr[0], qv); unpack8(Qr[1], qv + 8);
  }

  float s[16];
#pragma unroll
  for (int k = 0; k < 16; ++k) {
    const u32x4* Kr = (const u32x4*)&sm[w][1][k * 64 + p * 16];
    float kv[16];
    unpack8(Kr[0], kv); unpack8(Kr[1], kv + 8);
    float d = 0.f;
#pragma unroll
    for (int i = 0; i < 16; ++i) d = fmaf(qv[i], kv[i], d);
    d += __shfl_xor(d, 1);  // reduce over dim-quarters
    d += __shfl_xor(d, 2);
    s[k] = d * 0.125f;  // 1/sqrt(64)
  }

  float m = s[0];
#pragma unroll
  for (int k = 1; k < 16; ++k) m = fmaxf(m, s[k]);
  float sum = 0.f;
#pragma unroll
  for (int k = 0; k < 16; ++k) { s[k] = exp2f((s[k] - m) * 1.44269504f); sum += s[k]; }
  const float inv = 1.0f / sum;

  float acc[16];
#pragma unroll
  for (int i = 0; i < 16; ++i) acc[i] = 0.f;
#pragma unroll
  for (int k = 0; k < 16; ++k) {
    const u32x4* Vr = (const u32x4*)&sm[w][2][k * 64 + p * 16];
    float vv[16];
    unpack8(Vr[0], vv); unpack8(Vr[1], vv + 8);
    const float pw = s[k] * inv;
#pragma unroll
    for (int i = 0; i < 16; ++i) acc[i] = fmaf(pw, vv[i], acc[i]);
  }

  u16* Or = O + t * 1024 + q * 64 + p * 16;
#pragma unroll
  for (int h = 0; h < 2; ++h) {
    u16x8 o;
#pragma unroll
    for (int i = 0; i < 8; ++i) o[i] = f2bf(acc[h * 8 + i]);
    *(u16x8*)(Or + h * 8) = o;
  }
}

// ---------------- launch ----------------
extern "C" void kernel_launch(void* const* d_in, const int* in_sizes, int n_in,
                              void* d_out, int out_size, void* d_ws, size_t ws_size,
                              hipStream_t stream) {
  const float* H  = (const float*)d_in[0];
  const float* Wq = (const float*)d_in[1];
  const float* bq = (const float*)d_in[2];
  const float* Wk = (const float*)d_in[3];
  const float* bk = (const float*)d_in[4];
  const float* Wv = (const float*)d_in[5];
  const float* bv = (const float*)d_in[6];
  const float* Wo = (const float*)d_in[7];
  const float* bo = (const float*)d_in[8];

  const int M = in_sizes[0] / 1024;  // 65536 tokens
  const int K = 1024, N = 1024;
  const size_t sz = (size_t)M * 1024;

  u16* ws  = (u16*)d_ws;
  u16* Hb  = ws;            // M*1024 bf16 (reused as attended after QKV gemms)
  u16* Qb  = ws + sz;
  u16* Kb  = ws + 2 * sz;
  u16* Vb  = ws + 3 * sz;
  u16* Wqb = ws + 4 * sz;
  u16* Wkb = Wqb + (1 << 20);
  u16* Wvb = Wqb + 2 * (1 << 20);
  u16* Wob = Wqb + 3 * (1 << 20);
  u16* Ab  = Hb;

  const long nH = (long)M * 1024;
  cast_kernel<<<dim3(nH / 2048), dim3(256), 0, stream>>>(H, Hb, nH);
  cast_w4<<<dim3(512, 4), dim3(256), 0, stream>>>(Wq, Wk, Wv, Wo, Wqb, Wkb, Wvb, Wob);

  // flattened (x,y) grid = 4096 blocks (divisible by 8 for the XCD swizzle); z = output slice
  gemm_bt<false><<<dim3((M / 128) * (N / 128), 1, 3), dim3(256), 0, stream>>>(
      Hb, Wqb, Wkb, Wvb, bq, bk, bv, Qb, Kb, Vb, N, K);

  attn_kernel<<<dim3(M / 4), dim3(256), 0, stream>>>(Qb, Kb, Vb, Ab);

  gemm_bt<true><<<dim3((M / 128) * (N / 128), 1, 1), dim3(256), 0, stream>>>(
      Ab, Wob, Wob, Wob, bo, bo, bo, d_out, d_out, d_out, N, K);
}